// Round 1
// baseline (539.925 us; speedup 1.0000x reference)
//
#include <hip/hip_runtime.h>

// Problem constants (from reference)
constexpr int NN = 50000;
constexpr int EE = 800000;
constexpr int FF = 64;     // features
constexpr int HH = 256;    // hidden
constexpr int DD = 64;     // out dim
constexpr int GG = 128;    // graphs
constexpr float MIN_SCORE = 0.05f;
constexpr float TOL = 1e-7f;
constexpr float EPSV = 1e-14f;

// ---- ordered-uint encoding for float atomicMax over arbitrary-sign floats ----
__device__ inline unsigned enc_f(float v) {
    unsigned u = __float_as_uint(v);
    return (u & 0x80000000u) ? ~u : (u | 0x80000000u);
}
__device__ inline float dec_f(unsigned e) {
    return (e & 0x80000000u) ? __uint_as_float(e & 0x7fffffffu)
                             : __uint_as_float(~e);
}

// K1: s[i] = dot(x[i,:], pw); per-graph segment max via atomicMax on encoded bits.
// One 64-lane wave per node (4 nodes per 256-thread block).
__global__ void k_score_dot(const float* __restrict__ x, const float* __restrict__ pw,
                            const int* __restrict__ batch, float* __restrict__ s,
                            unsigned* __restrict__ smax_enc) {
    int node = blockIdx.x * 4 + (threadIdx.x >> 6);
    if (node >= NN) return;
    int lane = threadIdx.x & 63;
    float v = x[(size_t)node * FF + lane] * pw[lane];
#pragma unroll
    for (int off = 32; off; off >>= 1) v += __shfl_down(v, off);
    if (lane == 0) {
        s[node] = v;
        atomicMax(&smax_enc[batch[node]], enc_f(v));
    }
}

// K2: e = exp(s - smax[g]); store in-place; accumulate per-graph sum.
__global__ void k_exp(const int* __restrict__ batch, float* __restrict__ s,
                      const unsigned* __restrict__ smax_enc, float* __restrict__ esum) {
    int i = blockIdx.x * blockDim.x + threadIdx.x;
    if (i >= NN) return;
    int b = batch[i];
    float ev = expf(s[i] - dec_f(smax_enc[b]));
    s[i] = ev;
    atomicAdd(&esum[b], ev);
}

// K3: score = e / esum[g]; per-graph score max (scores > 0 so raw uint bits order).
__global__ void k_norm(const int* __restrict__ batch, float* __restrict__ s,
                       const float* __restrict__ esum, unsigned* __restrict__ scoremax) {
    int i = blockIdx.x * blockDim.x + threadIdx.x;
    if (i >= NN) return;
    int b = batch[i];
    float sc = s[i] / esum[b];
    s[i] = sc;
    atomicMax(&scoremax[b], __float_as_uint(sc));
}

// K4: mask + compaction + per-kept KL accumulation + zero agg rows of kept nodes.
__global__ void k_mask(const int* __restrict__ batch, const float* __restrict__ s,
                       const unsigned* __restrict__ scoremax, const float* __restrict__ na,
                       int* __restrict__ comp, int* __restrict__ kept_idx,
                       int* __restrict__ keptcnt, float* __restrict__ klsum,
                       float* __restrict__ cntk, float* __restrict__ aggc) {
    int i = blockIdx.x * blockDim.x + threadIdx.x;
    if (i >= NN) return;
    int b = batch[i];
    float sc = s[i];
    float thr = fminf(__uint_as_float(scoremax[b]) - TOL, MIN_SCORE);
    if (sc > thr) {
        int c = atomicAdd(keptcnt, 1);
        comp[i] = c;
        kept_idx[c] = i;
        float* row = aggc + (size_t)c * DD;
#pragma unroll
        for (int f = 0; f < DD; ++f) row[f] = 0.f;
        float t = na[i];
        float tlogt = (t > 0.f) ? t * logf(t) : 0.f;
        float kl = tlogt - t * logf(sc + EPSV);
        atomicAdd(&klsum[b], kl);
        atomicAdd(&cntk[b], 1.0f);
    } else {
        comp[i] = -1;
    }
}

// K5: edge scan 1. For edges with kept dst: scatter x[src] into aggc[comp[dst]].
// Also build compact list of edges with BOTH endpoints kept (for conv2).
__global__ void k_edge1(const int* __restrict__ ei, const int* __restrict__ comp,
                        const float* __restrict__ x, float* __restrict__ aggc,
                        int* __restrict__ elist, int* __restrict__ ecnt) {
    int e = blockIdx.x * blockDim.x + threadIdx.x;
    if (e >= EE) return;
    int d = ei[EE + e];          // dst
    int cd = comp[d];
    if (cd < 0) return;
    int sn = ei[e];              // src
    const float* xr = x + (size_t)sn * FF;
    float* ar = aggc + (size_t)cd * DD;
#pragma unroll
    for (int f = 0; f < DD; ++f) atomicAdd(&ar[f], xr[f]);
    int cs = comp[sn];
    if (cs >= 0) {
        int j = atomicAdd(ecnt, 1);
        elist[2 * j] = cs;
        elist[2 * j + 1] = cd;
    }
}

// K6: GIN1 MLP for kept nodes only. Block (256 thr) per node, persistent over K.
// z = x[i] + agg1; h1 = relu(relu(z@W1a+b1a)@W1b+b1b); xp = h1*score.
// Re-zeroes aggc row for reuse as agg2 buffer.
__global__ __launch_bounds__(256) void k_mlp1(
        const int* __restrict__ kept_idx, const int* __restrict__ keptcnt,
        const float* __restrict__ x, float* __restrict__ aggc,
        const float* __restrict__ s,
        const float* __restrict__ W1a, const float* __restrict__ b1a,
        const float* __restrict__ W1b, const float* __restrict__ b1b,
        float* __restrict__ xpc) {
    __shared__ float z[FF];
    __shared__ float hid[HH];
    int K = *keptcnt;
    int t = threadIdx.x;
    for (int c = blockIdx.x; c < K; c += gridDim.x) {
        int i = kept_idx[c];
        if (t < FF) {
            z[t] = x[(size_t)i * FF + t] + aggc[(size_t)c * DD + t];
            aggc[(size_t)c * DD + t] = 0.f;   // reset for agg2 phase
        }
        __syncthreads();
        float acc = b1a[t];
#pragma unroll
        for (int f = 0; f < FF; ++f) acc += z[f] * W1a[f * HH + t];
        hid[t] = fmaxf(acc, 0.f);
        __syncthreads();
        if (t < DD) {
            float a2 = b1b[t];
#pragma unroll 8
            for (int h = 0; h < HH; ++h) a2 += hid[h] * W1b[h * DD + t];
            float h1 = fmaxf(a2, 0.f);
            xpc[(size_t)c * DD + t] = h1 * s[i];
        }
        __syncthreads();
    }
}

// K7: edge scan 2 over surviving-edge list: agg2[cd] += xp[cs].
__global__ void k_edge2(const int* __restrict__ elist, const int* __restrict__ ecnt,
                        const float* __restrict__ xpc, float* __restrict__ aggc) {
    int total = (*ecnt) * DD;
    int stride = gridDim.x * blockDim.x;
    for (int idx = blockIdx.x * blockDim.x + threadIdx.x; idx < total; idx += stride) {
        int e = idx >> 6;
        int f = idx & 63;
        int cs = elist[2 * e];
        int cd = elist[2 * e + 1];
        atomicAdd(&aggc[(size_t)cd * DD + f], xpc[(size_t)cs * DD + f]);
    }
}

// K8: GIN2 MLP for kept nodes; accumulate per-graph feature sums.
__global__ __launch_bounds__(256) void k_mlp2(
        const int* __restrict__ kept_idx, const int* __restrict__ keptcnt,
        const int* __restrict__ batch,
        const float* __restrict__ xpc, const float* __restrict__ aggc,
        const float* __restrict__ W2a, const float* __restrict__ b2a,
        const float* __restrict__ W2b, const float* __restrict__ b2b,
        float* __restrict__ gsum) {
    __shared__ float z[DD];
    __shared__ float hid[HH];
    int K = *keptcnt;
    int t = threadIdx.x;
    for (int c = blockIdx.x; c < K; c += gridDim.x) {
        int i = kept_idx[c];
        if (t < DD) z[t] = xpc[(size_t)c * DD + t] + aggc[(size_t)c * DD + t];
        __syncthreads();
        float acc = b2a[t];
#pragma unroll
        for (int f = 0; f < DD; ++f) acc += z[f] * W2a[f * HH + t];
        hid[t] = fmaxf(acc, 0.f);
        __syncthreads();
        if (t < DD) {
            float a2 = b2b[t];
#pragma unroll 8
            for (int h = 0; h < HH; ++h) a2 += hid[h] * W2b[h * DD + t];
            float v = fmaxf(a2, 0.f);
            atomicAdd(&gsum[(size_t)batch[i] * DD + t], v);
        }
        __syncthreads();
    }
}

// K9: finalize: xg = gsum@Wl + bl; attn_loss = klsum/max(cnt,1); ratio.
__global__ void k_final(const float* __restrict__ gsum, const float* __restrict__ Wl,
                        const float* __restrict__ bl, const float* __restrict__ klsum,
                        const float* __restrict__ cntk, const int* __restrict__ keptcnt,
                        float* __restrict__ out) {
    int g = threadIdx.x;
    if (g < GG) {
        float acc = 0.f;
#pragma unroll 8
        for (int d = 0; d < DD; ++d) acc += gsum[(size_t)g * DD + d] * Wl[d];
        out[g] = acc + bl[0];
        out[GG + g] = klsum[g] / fmaxf(cntk[g], 1.0f);
    }
    if (g == 0) out[2 * GG] = (float)(*keptcnt) / (float)NN;
}

extern "C" void kernel_launch(void* const* d_in, const int* in_sizes, int n_in,
                              void* d_out, int out_size, void* d_ws, size_t ws_size,
                              hipStream_t stream) {
    const float* x   = (const float*)d_in[0];
    const float* na  = (const float*)d_in[1];
    const float* W1a = (const float*)d_in[2];
    const float* b1a = (const float*)d_in[3];
    const float* W1b = (const float*)d_in[4];
    const float* b1b = (const float*)d_in[5];
    const float* pw  = (const float*)d_in[6];
    const float* W2a = (const float*)d_in[7];
    const float* b2a = (const float*)d_in[8];
    const float* W2b = (const float*)d_in[9];
    const float* b2b = (const float*)d_in[10];
    const float* Wl  = (const float*)d_in[11];
    const float* bl  = (const float*)d_in[12];
    const int* ei    = (const int*)d_in[13];
    const int* batch = (const int*)d_in[14];
    float* out = (float*)d_out;

    // ---- workspace layout (256B aligned blocks) ----
    char* w = (char*)d_ws;
    auto alloc = [&](size_t bytes) -> void* {
        void* p = (void*)w;
        w += (bytes + 255) & ~(size_t)255;
        return p;
    };
    // zero-initialized region (contiguous, one memsetAsync)
    unsigned* smax_enc = (unsigned*)alloc(GG * 4);
    float*    esum     = (float*)alloc(GG * 4);
    unsigned* scoremax = (unsigned*)alloc(GG * 4);
    float*    klsum    = (float*)alloc(GG * 4);
    float*    cntk     = (float*)alloc(GG * 4);
    float*    gsum     = (float*)alloc((size_t)GG * DD * 4);
    int*      keptcnt  = (int*)alloc(4);
    int*      ecnt     = (int*)alloc(4);
    size_t zbytes = (size_t)(w - (char*)d_ws);
    // non-zeroed scratch
    float* s        = (float*)alloc((size_t)NN * 4);
    int*   comp     = (int*)alloc((size_t)NN * 4);
    int*   kept_idx = (int*)alloc((size_t)NN * 4);
    float* aggc     = (float*)alloc((size_t)NN * DD * 4);
    float* xpc      = (float*)alloc((size_t)NN * DD * 4);
    int*   elist    = (int*)alloc((size_t)2 * EE * 4);
    (void)ws_size; (void)in_sizes; (void)n_in; (void)out_size;

    hipMemsetAsync(d_ws, 0, zbytes, stream);

    k_score_dot<<<(NN + 3) / 4, 256, 0, stream>>>(x, pw, batch, s, smax_enc);
    k_exp<<<(NN + 255) / 256, 256, 0, stream>>>(batch, s, smax_enc, esum);
    k_norm<<<(NN + 255) / 256, 256, 0, stream>>>(batch, s, esum, scoremax);
    k_mask<<<(NN + 255) / 256, 256, 0, stream>>>(batch, s, scoremax, na, comp,
                                                 kept_idx, keptcnt, klsum, cntk, aggc);
    k_edge1<<<(EE + 255) / 256, 256, 0, stream>>>(ei, comp, x, aggc, elist, ecnt);
    k_mlp1<<<256, 256, 0, stream>>>(kept_idx, keptcnt, x, aggc, s,
                                    W1a, b1a, W1b, b1b, xpc);
    k_edge2<<<256, 256, 0, stream>>>(elist, ecnt, xpc, aggc);
    k_mlp2<<<256, 256, 0, stream>>>(kept_idx, keptcnt, batch, xpc, aggc,
                                    W2a, b2a, W2b, b2b, gsum);
    k_final<<<1, 128, 0, stream>>>(gsum, Wl, bl, klsum, cntk, keptcnt, out);
}

// Round 2
// 65.961 us; speedup vs baseline: 8.1856x; 8.1856x over previous
//
#include <hip/hip_runtime.h>

// Problem constants (from reference)
constexpr int NN = 50000;
constexpr int EE = 800000;
constexpr int FF = 64;     // features
constexpr int HH = 256;    // hidden
constexpr int DD = 64;     // out dim
constexpr int GG = 128;    // graphs
constexpr float MIN_SCORE = 0.05f;
constexpr float TOL = 1e-7f;
constexpr float EPSV = 1e-14f;

// K1: s[i] = dot(x[i,:], pw). Pure streaming, no atomics.
// 16 lanes per node (float4 each), 4 nodes per wave, 16 nodes per 256-thr block.
__global__ __launch_bounds__(256) void k_score_dot(
        const float4* __restrict__ x4, const float4* __restrict__ pw4,
        float* __restrict__ s) {
    int wid = threadIdx.x >> 6, lane = threadIdx.x & 63;
    int node = blockIdx.x * 16 + wid * 4 + (lane >> 4);
    int l4 = lane & 15;
    if (node >= NN) return;
    float4 xv = x4[(size_t)node * 16 + l4];
    float4 pv = pw4[l4];
    float v = xv.x * pv.x + xv.y * pv.y + xv.z * pv.z + xv.w * pv.w;
#pragma unroll
    for (int off = 1; off < 16; off <<= 1) v += __shfl_xor(v, off);
    if (l4 == 0) s[node] = v;
}

// K2: per-graph softmax + threshold + mask + compaction + KL. One block per graph.
// Graph g owns nodes [ceil(g*N/G), ceil((g+1)*N/G)) -- contiguous, <=391 nodes.
__global__ __launch_bounds__(256) void k_pool(
        const float* __restrict__ s, const float* __restrict__ na,
        int* __restrict__ comp, int* __restrict__ kept_idx,
        float* __restrict__ kscore, int* __restrict__ keptcnt,
        float* __restrict__ klsum, float* __restrict__ cntk,
        float* __restrict__ aggc) {
    int g = blockIdx.x;
    int start = (g * NN + GG - 1) / GG;
    int end   = ((g + 1) * NN + GG - 1) / GG;
    int cnt = end - start;                 // 390 or 391
    int t = threadIdx.x;
    int wid = t >> 6, lane = t & 63;
    __shared__ float ev[392];
    __shared__ float red[4];
    __shared__ float sh_smax, sh_esum, sh_kl;
    __shared__ int sh_cnt;

    // pass A: load + block max
    float v0 = (t < cnt) ? s[start + t] : -3.4e38f;
    float v1 = (t + 256 < cnt) ? s[start + t + 256] : -3.4e38f;
    if (t < cnt) ev[t] = v0;
    if (t + 256 < cnt) ev[t + 256] = v1;
    float m = fmaxf(v0, v1);
#pragma unroll
    for (int off = 32; off; off >>= 1) m = fmaxf(m, __shfl_xor(m, off));
    if (lane == 0) red[wid] = m;
    __syncthreads();
    if (t == 0) {
        sh_smax = fmaxf(fmaxf(red[0], red[1]), fmaxf(red[2], red[3]));
        sh_kl = 0.f; sh_cnt = 0;
    }
    __syncthreads();
    float smax = sh_smax;

    // pass B: exp + block sum
    float e0 = (t < cnt) ? expf(ev[t] - smax) : 0.f;
    float e1 = (t + 256 < cnt) ? expf(ev[t + 256] - smax) : 0.f;
    if (t < cnt) ev[t] = e0;
    if (t + 256 < cnt) ev[t + 256] = e1;
    float ssum = e0 + e1;
#pragma unroll
    for (int off = 32; off; off >>= 1) ssum += __shfl_xor(ssum, off);
    if (lane == 0) red[wid] = ssum;
    __syncthreads();
    if (t == 0) sh_esum = red[0] + red[1] + red[2] + red[3];
    __syncthreads();
    float esum = sh_esum;

    // scoremax = (max e)/esum = 1/esum exactly (max element: exp(0)=1)
    float thresh = fminf(1.0f / esum - TOL, MIN_SCORE);

    // pass C: mask + compact + KL
    auto handle = [&](int j, float e) {
        if (j >= cnt) return;
        int i = start + j;
        float sc = e / esum;
        if (sc > thresh) {
            int c = atomicAdd(keptcnt, 1);
            comp[i] = c;
            kept_idx[c] = i;
            kscore[c] = sc;
            float* row = aggc + (size_t)c * DD;
#pragma unroll
            for (int f = 0; f < DD; ++f) row[f] = 0.f;
            float tt = na[i];
            float tlogt = (tt > 0.f) ? tt * logf(tt) : 0.f;
            float kl = tlogt - tt * logf(sc + EPSV);
            atomicAdd(&sh_kl, kl);
            atomicAdd(&sh_cnt, 1);
        } else {
            comp[i] = -1;
        }
    };
    handle(t, e0);
    handle(t + 256, e1);
    __syncthreads();
    if (t == 0) {
        klsum[g] = sh_kl;
        cntk[g] = (float)sh_cnt;
    }
}

// K3: edge scan. For edges with kept dst: scatter x[src] into aggc[comp[dst]].
// Build compact list of edges with BOTH endpoints kept (for conv2).
__global__ __launch_bounds__(256) void k_edge1(
        const int* __restrict__ ei, const int* __restrict__ comp,
        const float* __restrict__ x, float* __restrict__ aggc,
        int* __restrict__ elist, int* __restrict__ ecnt) {
    int e4 = blockIdx.x * blockDim.x + threadIdx.x;
    if (e4 >= EE / 4) return;
    int4 dv = ((const int4*)(ei + EE))[e4];
    int ds[4] = {dv.x, dv.y, dv.z, dv.w};
#pragma unroll
    for (int k = 0; k < 4; ++k) {
        int cd = comp[ds[k]];
        if (cd < 0) continue;
        int e = e4 * 4 + k;
        int sn = ei[e];
        const float4* xr = (const float4*)(x + (size_t)sn * FF);
        float* ar = aggc + (size_t)cd * DD;
#pragma unroll
        for (int f4 = 0; f4 < 16; ++f4) {
            float4 xv = xr[f4];
            atomicAdd(&ar[f4 * 4 + 0], xv.x);
            atomicAdd(&ar[f4 * 4 + 1], xv.y);
            atomicAdd(&ar[f4 * 4 + 2], xv.z);
            atomicAdd(&ar[f4 * 4 + 3], xv.w);
        }
        int cs = comp[sn];
        if (cs >= 0) {
            int j = atomicAdd(ecnt, 1);
            elist[2 * j] = cs;
            elist[2 * j + 1] = cd;
        }
    }
}

// K4: GIN1 MLP for kept nodes only. Block (256 thr) per node, persistent over K.
__global__ __launch_bounds__(256) void k_mlp1(
        const int* __restrict__ kept_idx, const int* __restrict__ keptcnt,
        const float* __restrict__ x, float* __restrict__ aggc,
        const float* __restrict__ kscore,
        const float* __restrict__ W1a, const float* __restrict__ b1a,
        const float* __restrict__ W1b, const float* __restrict__ b1b,
        float* __restrict__ xpc) {
    __shared__ float z[FF];
    __shared__ float hid[HH];
    int K = *keptcnt;
    int t = threadIdx.x;
    for (int c = blockIdx.x; c < K; c += gridDim.x) {
        int i = kept_idx[c];
        if (t < FF) {
            z[t] = x[(size_t)i * FF + t] + aggc[(size_t)c * DD + t];
            aggc[(size_t)c * DD + t] = 0.f;   // reset for agg2 phase
        }
        __syncthreads();
        float acc = b1a[t];
#pragma unroll
        for (int f = 0; f < FF; ++f) acc += z[f] * W1a[f * HH + t];
        hid[t] = fmaxf(acc, 0.f);
        __syncthreads();
        if (t < DD) {
            float a2 = b1b[t];
#pragma unroll 8
            for (int h = 0; h < HH; ++h) a2 += hid[h] * W1b[h * DD + t];
            float h1 = fmaxf(a2, 0.f);
            xpc[(size_t)c * DD + t] = h1 * kscore[c];
        }
        __syncthreads();
    }
}

// K5: edge scan 2 over surviving-edge list: agg2[cd] += xp[cs].
__global__ void k_edge2(const int* __restrict__ elist, const int* __restrict__ ecnt,
                        const float* __restrict__ xpc, float* __restrict__ aggc) {
    int total = (*ecnt) * DD;
    int stride = gridDim.x * blockDim.x;
    for (int idx = blockIdx.x * blockDim.x + threadIdx.x; idx < total; idx += stride) {
        int e = idx >> 6;
        int f = idx & 63;
        int cs = elist[2 * e];
        int cd = elist[2 * e + 1];
        atomicAdd(&aggc[(size_t)cd * DD + f], xpc[(size_t)cs * DD + f]);
    }
}

// K6: GIN2 MLP for kept nodes; accumulate per-graph feature sums.
__global__ __launch_bounds__(256) void k_mlp2(
        const int* __restrict__ kept_idx, const int* __restrict__ keptcnt,
        const float* __restrict__ xpc, const float* __restrict__ aggc,
        const float* __restrict__ W2a, const float* __restrict__ b2a,
        const float* __restrict__ W2b, const float* __restrict__ b2b,
        float* __restrict__ gsum) {
    __shared__ float z[DD];
    __shared__ float hid[HH];
    int K = *keptcnt;
    int t = threadIdx.x;
    for (int c = blockIdx.x; c < K; c += gridDim.x) {
        int i = kept_idx[c];
        if (t < DD) z[t] = xpc[(size_t)c * DD + t] + aggc[(size_t)c * DD + t];
        __syncthreads();
        float acc = b2a[t];
#pragma unroll
        for (int f = 0; f < DD; ++f) acc += z[f] * W2a[f * HH + t];
        hid[t] = fmaxf(acc, 0.f);
        __syncthreads();
        if (t < DD) {
            float a2 = b2b[t];
#pragma unroll 8
            for (int h = 0; h < HH; ++h) a2 += hid[h] * W2b[h * DD + t];
            float v = fmaxf(a2, 0.f);
            int gph = (i * GG) / NN;          // == batch[i] (sorted layout)
            atomicAdd(&gsum[(size_t)gph * DD + t], v);
        }
        __syncthreads();
    }
}

// K7: finalize: xg = gsum@Wl + bl; attn_loss = klsum/max(cnt,1); ratio.
__global__ void k_final(const float* __restrict__ gsum, const float* __restrict__ Wl,
                        const float* __restrict__ bl, const float* __restrict__ klsum,
                        const float* __restrict__ cntk, const int* __restrict__ keptcnt,
                        float* __restrict__ out) {
    int g = threadIdx.x;
    if (g < GG) {
        float acc = 0.f;
#pragma unroll 8
        for (int d = 0; d < DD; ++d) acc += gsum[(size_t)g * DD + d] * Wl[d];
        out[g] = acc + bl[0];
        out[GG + g] = klsum[g] / fmaxf(cntk[g], 1.0f);
    }
    if (g == 0) out[2 * GG] = (float)(*keptcnt) / (float)NN;
}

extern "C" void kernel_launch(void* const* d_in, const int* in_sizes, int n_in,
                              void* d_out, int out_size, void* d_ws, size_t ws_size,
                              hipStream_t stream) {
    const float* x   = (const float*)d_in[0];
    const float* na  = (const float*)d_in[1];
    const float* W1a = (const float*)d_in[2];
    const float* b1a = (const float*)d_in[3];
    const float* W1b = (const float*)d_in[4];
    const float* b1b = (const float*)d_in[5];
    const float* pw  = (const float*)d_in[6];
    const float* W2a = (const float*)d_in[7];
    const float* b2a = (const float*)d_in[8];
    const float* W2b = (const float*)d_in[9];
    const float* b2b = (const float*)d_in[10];
    const float* Wl  = (const float*)d_in[11];
    const float* bl  = (const float*)d_in[12];
    const int* ei    = (const int*)d_in[13];
    float* out = (float*)d_out;

    // ---- workspace layout (256B aligned blocks) ----
    char* w = (char*)d_ws;
    auto alloc = [&](size_t bytes) -> void* {
        void* p = (void*)w;
        w += (bytes + 255) & ~(size_t)255;
        return p;
    };
    // zero-initialized region (contiguous, one memsetAsync)
    int*   keptcnt = (int*)alloc(4);
    int*   ecnt    = (int*)alloc(4);
    float* gsum    = (float*)alloc((size_t)GG * DD * 4);
    size_t zbytes = (size_t)(w - (char*)d_ws);
    // non-zeroed scratch
    float* s        = (float*)alloc((size_t)NN * 4);
    int*   comp     = (int*)alloc((size_t)NN * 4);
    int*   kept_idx = (int*)alloc((size_t)NN * 4);
    float* kscore   = (float*)alloc((size_t)NN * 4);
    float* klsum    = (float*)alloc(GG * 4);
    float* cntk     = (float*)alloc(GG * 4);
    float* aggc     = (float*)alloc((size_t)NN * DD * 4);
    float* xpc      = (float*)alloc((size_t)NN * DD * 4);
    int*   elist    = (int*)alloc((size_t)2 * EE * 4);
    (void)ws_size; (void)in_sizes; (void)n_in; (void)out_size;

    hipMemsetAsync(d_ws, 0, zbytes, stream);

    k_score_dot<<<(NN + 15) / 16, 256, 0, stream>>>((const float4*)x,
                                                    (const float4*)pw, s);
    k_pool<<<GG, 256, 0, stream>>>(s, na, comp, kept_idx, kscore, keptcnt,
                                   klsum, cntk, aggc);
    k_edge1<<<(EE / 4 + 255) / 256, 256, 0, stream>>>(ei, comp, x, aggc, elist, ecnt);
    k_mlp1<<<128, 256, 0, stream>>>(kept_idx, keptcnt, x, aggc, kscore,
                                    W1a, b1a, W1b, b1b, xpc);
    k_edge2<<<128, 256, 0, stream>>>(elist, ecnt, xpc, aggc);
    k_mlp2<<<128, 256, 0, stream>>>(kept_idx, keptcnt, xpc, aggc,
                                    W2a, b2a, W2b, b2b, gsum);
    k_final<<<1, 128, 0, stream>>>(gsum, Wl, bl, klsum, cntk, keptcnt, out);
}

// Round 3
// 63.400 us; speedup vs baseline: 8.5162x; 1.0404x over previous
//
#include <hip/hip_runtime.h>

// Problem constants (from reference)
constexpr int NN = 50000;
constexpr int EE = 800000;
constexpr int FF = 64;     // features
constexpr int HH = 256;    // hidden
constexpr int DD = 64;     // out dim
constexpr int GG = 128;    // graphs
constexpr float MIN_SCORE = 0.05f;
constexpr float TOL = 1e-7f;
constexpr float EPSV = 1e-14f;

// K1: s[i] = dot(x[i,:], pw). Pure streaming, no atomics.
// Also zeroes the small accumulator region (keptcnt/ecnt/gsum) — replaces the
// 40 µs rocclr fillBuffer dispatch seen in R2 profiling.
__global__ __launch_bounds__(256) void k_score_dot(
        const float4* __restrict__ x4, const float4* __restrict__ pw4,
        float* __restrict__ s, unsigned* __restrict__ zbuf, int zwords) {
    int gid = blockIdx.x * 256 + threadIdx.x;
    if (gid < zwords) zbuf[gid] = 0u;
    int wid = threadIdx.x >> 6, lane = threadIdx.x & 63;
    int node = blockIdx.x * 16 + wid * 4 + (lane >> 4);
    int l4 = lane & 15;
    if (node >= NN) return;
    float4 xv = x4[(size_t)node * 16 + l4];
    float4 pv = pw4[l4];
    float v = xv.x * pv.x + xv.y * pv.y + xv.z * pv.z + xv.w * pv.w;
#pragma unroll
    for (int off = 1; off < 16; off <<= 1) v += __shfl_xor(v, off);
    if (l4 == 0) s[node] = v;
}

// K2: per-graph softmax + threshold + mask + compaction + KL. One block per graph.
// Graph g owns nodes [ceil(g*N/G), ceil((g+1)*N/G)) -- contiguous, <=391 nodes.
__global__ __launch_bounds__(256) void k_pool(
        const float* __restrict__ s, const float* __restrict__ na,
        int* __restrict__ comp, int* __restrict__ kept_idx,
        float* __restrict__ kscore, int* __restrict__ keptcnt,
        float* __restrict__ klsum, float* __restrict__ cntk,
        float* __restrict__ aggc) {
    int g = blockIdx.x;
    int start = (g * NN + GG - 1) / GG;
    int end   = ((g + 1) * NN + GG - 1) / GG;
    int cnt = end - start;                 // 390 or 391
    int t = threadIdx.x;
    int wid = t >> 6, lane = t & 63;
    __shared__ float ev[392];
    __shared__ float red[4];
    __shared__ float sh_smax, sh_esum, sh_kl;
    __shared__ int sh_cnt;

    // pass A: load + block max
    float v0 = (t < cnt) ? s[start + t] : -3.4e38f;
    float v1 = (t + 256 < cnt) ? s[start + t + 256] : -3.4e38f;
    if (t < cnt) ev[t] = v0;
    if (t + 256 < cnt) ev[t + 256] = v1;
    float m = fmaxf(v0, v1);
#pragma unroll
    for (int off = 32; off; off >>= 1) m = fmaxf(m, __shfl_xor(m, off));
    if (lane == 0) red[wid] = m;
    __syncthreads();
    if (t == 0) {
        sh_smax = fmaxf(fmaxf(red[0], red[1]), fmaxf(red[2], red[3]));
        sh_kl = 0.f; sh_cnt = 0;
    }
    __syncthreads();
    float smax = sh_smax;

    // pass B: exp + block sum
    float e0 = (t < cnt) ? expf(ev[t] - smax) : 0.f;
    float e1 = (t + 256 < cnt) ? expf(ev[t + 256] - smax) : 0.f;
    if (t < cnt) ev[t] = e0;
    if (t + 256 < cnt) ev[t + 256] = e1;
    float ssum = e0 + e1;
#pragma unroll
    for (int off = 32; off; off >>= 1) ssum += __shfl_xor(ssum, off);
    if (lane == 0) red[wid] = ssum;
    __syncthreads();
    if (t == 0) sh_esum = red[0] + red[1] + red[2] + red[3];
    __syncthreads();
    float esum = sh_esum;

    // scoremax = (max e)/esum = 1/esum exactly (max element: exp(0)=1)
    float thresh = fminf(1.0f / esum - TOL, MIN_SCORE);

    // pass C: mask + compact + KL
    auto handle = [&](int j, float e) {
        if (j >= cnt) return;
        int i = start + j;
        float sc = e / esum;
        if (sc > thresh) {
            int c = atomicAdd(keptcnt, 1);
            comp[i] = c;
            kept_idx[c] = i;
            kscore[c] = sc;
            float* row = aggc + (size_t)c * DD;
#pragma unroll
            for (int f = 0; f < DD; ++f) row[f] = 0.f;
            float tt = na[i];
            float tlogt = (tt > 0.f) ? tt * logf(tt) : 0.f;
            float kl = tlogt - tt * logf(sc + EPSV);
            atomicAdd(&sh_kl, kl);
            atomicAdd(&sh_cnt, 1);
        } else {
            comp[i] = -1;
        }
    };
    handle(t, e0);
    handle(t + 256, e1);
    __syncthreads();
    if (t == 0) {
        klsum[g] = sh_kl;
        cntk[g] = (float)sh_cnt;
    }
}

// K3: edge scan. For edges with kept dst: scatter x[src] into aggc[comp[dst]].
// Build compact list of edges with BOTH endpoints kept (for conv2).
__global__ __launch_bounds__(256) void k_edge1(
        const int* __restrict__ ei, const int* __restrict__ comp,
        const float* __restrict__ x, float* __restrict__ aggc,
        int* __restrict__ elist, int* __restrict__ ecnt) {
    int e4 = blockIdx.x * blockDim.x + threadIdx.x;
    if (e4 >= EE / 4) return;
    int4 dv = ((const int4*)(ei + EE))[e4];
    int ds[4] = {dv.x, dv.y, dv.z, dv.w};
#pragma unroll
    for (int k = 0; k < 4; ++k) {
        int cd = comp[ds[k]];
        if (cd < 0) continue;
        int e = e4 * 4 + k;
        int sn = ei[e];
        const float4* xr = (const float4*)(x + (size_t)sn * FF);
        float* ar = aggc + (size_t)cd * DD;
#pragma unroll
        for (int f4 = 0; f4 < 16; ++f4) {
            float4 xv = xr[f4];
            atomicAdd(&ar[f4 * 4 + 0], xv.x);
            atomicAdd(&ar[f4 * 4 + 1], xv.y);
            atomicAdd(&ar[f4 * 4 + 2], xv.z);
            atomicAdd(&ar[f4 * 4 + 3], xv.w);
        }
        int cs = comp[sn];
        if (cs >= 0) {
            int j = atomicAdd(ecnt, 1);
            elist[2 * j] = cs;
            elist[2 * j + 1] = cd;
        }
    }
}

// K4: GIN1 MLP for kept nodes only. Block (256 thr) per node, persistent over K.
__global__ __launch_bounds__(256) void k_mlp1(
        const int* __restrict__ kept_idx, const int* __restrict__ keptcnt,
        const float* __restrict__ x, float* __restrict__ aggc,
        const float* __restrict__ kscore,
        const float* __restrict__ W1a, const float* __restrict__ b1a,
        const float* __restrict__ W1b, const float* __restrict__ b1b,
        float* __restrict__ xpc) {
    __shared__ float z[FF];
    __shared__ float hid[HH];
    int K = *keptcnt;
    int t = threadIdx.x;
    for (int c = blockIdx.x; c < K; c += gridDim.x) {
        int i = kept_idx[c];
        if (t < FF) {
            z[t] = x[(size_t)i * FF + t] + aggc[(size_t)c * DD + t];
            aggc[(size_t)c * DD + t] = 0.f;   // reset for agg2 phase
        }
        __syncthreads();
        float acc = b1a[t];
#pragma unroll
        for (int f = 0; f < FF; ++f) acc += z[f] * W1a[f * HH + t];
        hid[t] = fmaxf(acc, 0.f);
        __syncthreads();
        if (t < DD) {
            float a2 = b1b[t];
#pragma unroll 8
            for (int h = 0; h < HH; ++h) a2 += hid[h] * W1b[h * DD + t];
            float h1 = fmaxf(a2, 0.f);
            xpc[(size_t)c * DD + t] = h1 * kscore[c];
        }
        __syncthreads();
    }
}

// K5: edge scan 2 over surviving-edge list: agg2[cd] += xp[cs].
__global__ void k_edge2(const int* __restrict__ elist, const int* __restrict__ ecnt,
                        const float* __restrict__ xpc, float* __restrict__ aggc) {
    int total = (*ecnt) * DD;
    int stride = gridDim.x * blockDim.x;
    for (int idx = blockIdx.x * blockDim.x + threadIdx.x; idx < total; idx += stride) {
        int e = idx >> 6;
        int f = idx & 63;
        int cs = elist[2 * e];
        int cd = elist[2 * e + 1];
        atomicAdd(&aggc[(size_t)cd * DD + f], xpc[(size_t)cs * DD + f]);
    }
}

// K6: GIN2 MLP for kept nodes; accumulate per-graph feature sums.
__global__ __launch_bounds__(256) void k_mlp2(
        const int* __restrict__ kept_idx, const int* __restrict__ keptcnt,
        const float* __restrict__ xpc, const float* __restrict__ aggc,
        const float* __restrict__ W2a, const float* __restrict__ b2a,
        const float* __restrict__ W2b, const float* __restrict__ b2b,
        float* __restrict__ gsum) {
    __shared__ float z[DD];
    __shared__ float hid[HH];
    int K = *keptcnt;
    int t = threadIdx.x;
    for (int c = blockIdx.x; c < K; c += gridDim.x) {
        int i = kept_idx[c];
        if (t < DD) z[t] = xpc[(size_t)c * DD + t] + aggc[(size_t)c * DD + t];
        __syncthreads();
        float acc = b2a[t];
#pragma unroll
        for (int f = 0; f < DD; ++f) acc += z[f] * W2a[f * HH + t];
        hid[t] = fmaxf(acc, 0.f);
        __syncthreads();
        if (t < DD) {
            float a2 = b2b[t];
#pragma unroll 8
            for (int h = 0; h < HH; ++h) a2 += hid[h] * W2b[h * DD + t];
            float v = fmaxf(a2, 0.f);
            int gph = (i * GG) / NN;          // == batch[i] (sorted layout)
            atomicAdd(&gsum[(size_t)gph * DD + t], v);
        }
        __syncthreads();
    }
}

// K7: finalize: xg = gsum@Wl + bl; attn_loss = klsum/max(cnt,1); ratio.
__global__ void k_final(const float* __restrict__ gsum, const float* __restrict__ Wl,
                        const float* __restrict__ bl, const float* __restrict__ klsum,
                        const float* __restrict__ cntk, const int* __restrict__ keptcnt,
                        float* __restrict__ out) {
    int g = threadIdx.x;
    if (g < GG) {
        float acc = 0.f;
#pragma unroll 8
        for (int d = 0; d < DD; ++d) acc += gsum[(size_t)g * DD + d] * Wl[d];
        out[g] = acc + bl[0];
        out[GG + g] = klsum[g] / fmaxf(cntk[g], 1.0f);
    }
    if (g == 0) out[2 * GG] = (float)(*keptcnt) / (float)NN;
}

extern "C" void kernel_launch(void* const* d_in, const int* in_sizes, int n_in,
                              void* d_out, int out_size, void* d_ws, size_t ws_size,
                              hipStream_t stream) {
    const float* x   = (const float*)d_in[0];
    const float* na  = (const float*)d_in[1];
    const float* W1a = (const float*)d_in[2];
    const float* b1a = (const float*)d_in[3];
    const float* W1b = (const float*)d_in[4];
    const float* b1b = (const float*)d_in[5];
    const float* pw  = (const float*)d_in[6];
    const float* W2a = (const float*)d_in[7];
    const float* b2a = (const float*)d_in[8];
    const float* W2b = (const float*)d_in[9];
    const float* b2b = (const float*)d_in[10];
    const float* Wl  = (const float*)d_in[11];
    const float* bl  = (const float*)d_in[12];
    const int* ei    = (const int*)d_in[13];
    float* out = (float*)d_out;

    // ---- workspace layout (256B aligned blocks) ----
    char* w = (char*)d_ws;
    auto alloc = [&](size_t bytes) -> void* {
        void* p = (void*)w;
        w += (bytes + 255) & ~(size_t)255;
        return p;
    };
    // zero-initialized region (zeroed inside k_score_dot, contiguous)
    int*   keptcnt = (int*)alloc(4);
    int*   ecnt    = (int*)alloc(4);
    float* gsum    = (float*)alloc((size_t)GG * DD * 4);
    size_t zbytes = (size_t)(w - (char*)d_ws);
    int zwords = (int)(zbytes / 4);
    // non-zeroed scratch
    float* s        = (float*)alloc((size_t)NN * 4);
    int*   comp     = (int*)alloc((size_t)NN * 4);
    int*   kept_idx = (int*)alloc((size_t)NN * 4);
    float* kscore   = (float*)alloc((size_t)NN * 4);
    float* klsum    = (float*)alloc(GG * 4);
    float* cntk     = (float*)alloc(GG * 4);
    float* aggc     = (float*)alloc((size_t)NN * DD * 4);
    float* xpc      = (float*)alloc((size_t)NN * DD * 4);
    int*   elist    = (int*)alloc((size_t)2 * EE * 4);
    (void)ws_size; (void)in_sizes; (void)n_in; (void)out_size;

    k_score_dot<<<(NN + 15) / 16, 256, 0, stream>>>((const float4*)x,
                                                    (const float4*)pw, s,
                                                    (unsigned*)d_ws, zwords);
    k_pool<<<GG, 256, 0, stream>>>(s, na, comp, kept_idx, kscore, keptcnt,
                                   klsum, cntk, aggc);
    k_edge1<<<(EE / 4 + 255) / 256, 256, 0, stream>>>(ei, comp, x, aggc, elist, ecnt);
    k_mlp1<<<128, 256, 0, stream>>>(kept_idx, keptcnt, x, aggc, kscore,
                                    W1a, b1a, W1b, b1b, xpc);
    k_edge2<<<128, 256, 0, stream>>>(elist, ecnt, xpc, aggc);
    k_mlp2<<<128, 256, 0, stream>>>(kept_idx, keptcnt, xpc, aggc,
                                    W2a, b2a, W2b, b2b, gsum);
    k_final<<<1, 128, 0, stream>>>(gsum, Wl, bl, klsum, cntk, keptcnt, out);
}